// Round 2
// baseline (666.207 us; speedup 1.0000x reference)
//
#include <hip/hip_runtime.h>
#include <math.h>

#define NPIX 4096   // H*W
#define CR   64     // reduced channels
#define CIN  256    // input channels
#define HW   64     // H == W

// ---------------------------------------------------------------------------
// K1: 3x3 conv (pad=1, cross-correlation) + bias + BN(inference) + PReLU
//     -> e[b][d][n], n = h*64 + w
// ---------------------------------------------------------------------------
__global__ __launch_bounds__(256) void k_conv(
    const float* __restrict__ x, const float* __restrict__ cw,
    const float* __restrict__ cb, const float* __restrict__ gamma,
    const float* __restrict__ beta, const float* __restrict__ mean,
    const float* __restrict__ var, const float* __restrict__ pw,
    float* __restrict__ e) {
  const int wi = threadIdx.x;           // 0..63 (w)
  const int r  = threadIdx.y;           // 0..3
  const int h  = blockIdx.x * 4 + r;
  const int d  = blockIdx.y;            // 0..63
  const int b  = blockIdx.z;

  __shared__ float wl[CIN * 9];
  const int tid = r * 64 + wi;
  for (int i = tid; i < CIN * 9; i += 256) wl[i] = cw[d * CIN * 9 + i];
  __syncthreads();

  const float* xb = x + (size_t)b * CIN * NPIX;
  float acc = 0.f;
  for (int c = 0; c < CIN; ++c) {
    const float* xc = xb + (size_t)c * NPIX;
    const float* wc = wl + c * 9;
#pragma unroll
    for (int kh = 0; kh < 3; ++kh) {
      int hh = h + kh - 1;
      if (hh < 0 || hh >= HW) continue;
      const float* xr = xc + hh * HW;
#pragma unroll
      for (int kw = 0; kw < 3; ++kw) {
        int ww = wi + kw - 1;
        float xv = (ww >= 0 && ww < HW) ? xr[ww] : 0.f;
        acc = fmaf(wc[kh * 3 + kw], xv, acc);
      }
    }
  }
  float scale = gamma[d] / sqrtf(var[d] + 1e-5f);
  float y = (acc + cb[d] - mean[d]) * scale + beta[d];
  y = (y >= 0.f) ? y : pw[0] * y;
  e[((size_t)b * CR + d) * NPIX + h * HW + wi] = y;
}

// ---------------------------------------------------------------------------
// K2: sim[b][n][m] = sum_d e[b][d][n] * e[b][d][m]    (Gram, K=64)
//     64x64 output tile per block, 256 threads, 4x4 micro-tile
// ---------------------------------------------------------------------------
__global__ __launch_bounds__(256) void k_gram(const float* __restrict__ e,
                                              float* __restrict__ sim) {
  const int bm = blockIdx.x, bn = blockIdx.y, b = blockIdx.z;
  __shared__ __align__(16) float at[CR][64];
  __shared__ __align__(16) float bt[CR][64];
  const float* eb = e + (size_t)b * CR * NPIX;
  const int tid = threadIdx.x;
  for (int i = tid; i < CR * 64; i += 256) {
    int d = i >> 6, col = i & 63;
    at[d][col] = eb[(size_t)d * NPIX + bn * 64 + col];
    bt[d][col] = eb[(size_t)d * NPIX + bm * 64 + col];
  }
  __syncthreads();
  const int tx = tid & 15, ty = tid >> 4;
  float acc[4][4] = {};
  for (int d = 0; d < CR; ++d) {
    float4 a4 = *(const float4*)&at[d][ty * 4];
    float4 b4 = *(const float4*)&bt[d][tx * 4];
    float av[4] = {a4.x, a4.y, a4.z, a4.w};
    float bv[4] = {b4.x, b4.y, b4.z, b4.w};
#pragma unroll
    for (int i = 0; i < 4; ++i)
#pragma unroll
      for (int j = 0; j < 4; ++j) acc[i][j] = fmaf(av[i], bv[j], acc[i][j]);
  }
  float* sb = sim + (size_t)b * NPIX * NPIX;
#pragma unroll
  for (int i = 0; i < 4; ++i) {
    int n = bn * 64 + ty * 4 + i;
    float4 o = make_float4(acc[i][0], acc[i][1], acc[i][2], acc[i][3]);
    *(float4*)&sb[(size_t)n * NPIX + bm * 64 + tx * 4] = o;
  }
}

// ---------------------------------------------------------------------------
// K3: row-wise sparsemax, in place. One block per row (8192 rows).
//     Michelot's algorithm (exact, no sort). Sparsemax is shift-invariant,
//     so the reference's row-max subtraction is skipped (identical result).
// ---------------------------------------------------------------------------
__global__ __launch_bounds__(256) void k_sparsemax(float* __restrict__ sim) {
  float* rp = sim + (size_t)blockIdx.x * NPIX;
  const int tid = threadIdx.x;
  const int lane = tid & 63, wid = tid >> 6;

  float v[16];
  const float4* rv = (const float4*)rp;
#pragma unroll
  for (int i = 0; i < 4; ++i) {
    float4 t = rv[tid + i * 256];
    v[i * 4 + 0] = t.x; v[i * 4 + 1] = t.y;
    v[i * 4 + 2] = t.z; v[i * 4 + 3] = t.w;
  }

  __shared__ float ssum[4];
  __shared__ int   scnt[4];
  __shared__ float stau;
  __shared__ int   sctot;

  // initial tau from the full set
  float lsum = 0.f;
#pragma unroll
  for (int i = 0; i < 16; ++i) lsum += v[i];
  for (int o = 32; o > 0; o >>= 1) lsum += __shfl_down(lsum, o);
  if (lane == 0) ssum[wid] = lsum;
  __syncthreads();
  if (tid == 0)
    stau = (ssum[0] + ssum[1] + ssum[2] + ssum[3] - 1.f) * (1.f / NPIX);
  __syncthreads();
  float tau = stau;
  int cnt_prev = NPIX;

  for (int it = 0; it < 128; ++it) {
    float ls = 0.f; int lc = 0;
#pragma unroll
    for (int i = 0; i < 16; ++i)
      if (v[i] > tau) { ls += v[i]; ++lc; }
    for (int o = 32; o > 0; o >>= 1) {
      ls += __shfl_down(ls, o);
      lc += __shfl_down(lc, o);
    }
    if (lane == 0) { ssum[wid] = ls; scnt[wid] = lc; }
    __syncthreads();
    if (tid == 0) {
      float s = ssum[0] + ssum[1] + ssum[2] + ssum[3];
      int   c = scnt[0] + scnt[1] + scnt[2] + scnt[3];
      sctot = c;
      stau = (s - 1.f) / (float)c;
    }
    __syncthreads();
    int c = sctot;
    tau = stau;
    if (c == cnt_prev) break;   // support unchanged -> fixed point
    cnt_prev = c;
  }

  float4* wv = (float4*)rp;
#pragma unroll
  for (int i = 0; i < 4; ++i) {
    float4 t;
    t.x = fmaxf(v[i * 4 + 0] - tau, 0.f);
    t.y = fmaxf(v[i * 4 + 1] - tau, 0.f);
    t.z = fmaxf(v[i * 4 + 2] - tau, 0.f);
    t.w = fmaxf(v[i * 4 + 3] - tau, 0.f);
    wv[tid + i * 256] = t;
  }
}

// ---------------------------------------------------------------------------
// K4: out[b][c][m] = sum_n x[b][c][n] * p[b][n][m] + x[b][c][m]
//     fp32 GEMM [256 x 4096] @ [4096 x 4096], 64x64 tile, K-chunks of 32
// ---------------------------------------------------------------------------
__global__ __launch_bounds__(256) void k_out(const float* __restrict__ x,
                                             const float* __restrict__ p,
                                             float* __restrict__ out) {
  const int bm = blockIdx.x, bc = blockIdx.y, b = blockIdx.z;
  __shared__ __align__(16) float as[32][68];   // [k][c_local], padded
  __shared__ __align__(16) float bs[32][64];   // [k][m_local]
  const float* xb = x + (size_t)b * CIN * NPIX;
  const float* pb = p + (size_t)b * NPIX * NPIX;
  const int tid = threadIdx.x;
  const int tx = tid & 15, ty = tid >> 4;
  float acc[4][4] = {};

  for (int k0 = 0; k0 < NPIX; k0 += 32) {
#pragma unroll
    for (int u = 0; u < 2; ++u) {           // A: 64 c-rows x 32 k
      int idx = tid + u * 256;
      int row = idx >> 3;                   // 0..63
      int c4  = idx & 7;                    // 0..7
      float4 t = *(const float4*)&xb[(size_t)(bc * 64 + row) * NPIX + k0 + c4 * 4];
      as[c4 * 4 + 0][row] = t.x;
      as[c4 * 4 + 1][row] = t.y;
      as[c4 * 4 + 2][row] = t.z;
      as[c4 * 4 + 3][row] = t.w;
    }
#pragma unroll
    for (int u = 0; u < 2; ++u) {           // B: 32 k-rows x 64 m
      int idx = tid + u * 256;
      int row = idx >> 4;                   // 0..31
      int c4  = idx & 15;                   // 0..15
      *(float4*)&bs[row][c4 * 4] =
          *(const float4*)&pb[(size_t)(k0 + row) * NPIX + bm * 64 + c4 * 4];
    }
    __syncthreads();
#pragma unroll
    for (int kk = 0; kk < 32; ++kk) {
      float4 a4 = *(const float4*)&as[kk][ty * 4];
      float4 b4 = *(const float4*)&bs[kk][tx * 4];
      float av[4] = {a4.x, a4.y, a4.z, a4.w};
      float bv[4] = {b4.x, b4.y, b4.z, b4.w};
#pragma unroll
      for (int i = 0; i < 4; ++i)
#pragma unroll
        for (int j = 0; j < 4; ++j) acc[i][j] = fmaf(av[i], bv[j], acc[i][j]);
    }
    __syncthreads();
  }

  float* ob = out + (size_t)b * CIN * NPIX;
#pragma unroll
  for (int i = 0; i < 4; ++i) {
    int c = bc * 64 + ty * 4 + i;
    size_t off = (size_t)c * NPIX + bm * 64 + tx * 4;
    float4 xr = *(const float4*)&xb[off];
    float4 o = make_float4(acc[i][0] + xr.x, acc[i][1] + xr.y,
                           acc[i][2] + xr.z, acc[i][3] + xr.w);
    *(float4*)&ob[off] = o;
  }
}

// ---------------------------------------------------------------------------
extern "C" void kernel_launch(void* const* d_in, const int* in_sizes, int n_in,
                              void* d_out, int out_size, void* d_ws, size_t ws_size,
                              hipStream_t stream) {
  const float* x     = (const float*)d_in[0];
  const float* cw    = (const float*)d_in[1];
  const float* cb    = (const float*)d_in[2];
  const float* gamma = (const float*)d_in[3];
  const float* beta  = (const float*)d_in[4];
  const float* mean  = (const float*)d_in[5];
  const float* var   = (const float*)d_in[6];
  const float* pw    = (const float*)d_in[7];
  float* out = (float*)d_out;

  float* e   = (float*)d_ws;                         // 2 MiB
  float* sim = (float*)((char*)d_ws + (4u << 20));   // 128 MiB (p in place)

  k_conv<<<dim3(16, 64, 2), dim3(64, 4), 0, stream>>>(x, cw, cb, gamma, beta,
                                                      mean, var, pw, e);
  k_gram<<<dim3(64, 64, 2), 256, 0, stream>>>(e, sim);
  k_sparsemax<<<8192, 256, 0, stream>>>(sim);
  k_out<<<dim3(64, 4, 2), 256, 0, stream>>>(x, sim, out);
}

// Round 3
// 364.902 us; speedup vs baseline: 1.8257x; 1.8257x over previous
//
#include <hip/hip_runtime.h>
#include <math.h>

#define NPIX 4096
#define CR   64
#define CIN  256
#define HW   64

typedef __attribute__((ext_vector_type(8))) short s16x8;
typedef __attribute__((ext_vector_type(4))) float f32x4;

__device__ __forceinline__ unsigned short f2bf(float f) {
  union { float f; unsigned u; } a; a.f = f;
  return (unsigned short)((a.u + 0x7FFF + ((a.u >> 16) & 1)) >> 16);
}

// ---------------------------------------------------------------------------
// K1: conv partials, c-split=4. Block: 2h x 64w x 32d over 64 channels.
// Thread: 2h x 2w x 4d. x-slab + weights staged in LDS (x reused across d).
// ---------------------------------------------------------------------------
__global__ __launch_bounds__(256) void k_conv_part(
    const float* __restrict__ x, const float* __restrict__ cw,
    float* __restrict__ pp) {
  const int hg = blockIdx.x;          // h0 = hg*2
  const int dg = blockIdx.y;          // d0 = dg*32
  const int b  = blockIdx.z >> 2;
  const int cs = blockIdx.z & 3;      // c0 = cs*64
  const int h0 = hg * 2, d0 = dg * 32, c0 = cs * 64;
  const int tid = threadIdx.x;
  const int wp = tid & 31;            // w0 = wp*2
  const int dq = tid >> 5;            // 0..7 -> d = d0 + dq*4 + di
  const int w0 = wp * 2;

  __shared__ float xs[16][4][68];     // [c][row h0-1..h0+2][w+1], halo zeroed
  __shared__ float wl[16][9][32];     // [c][tap][d_local]

  float acc[2][2][4] = {};            // [hi][wi][di]

  for (int cc = 0; cc < 64; cc += 16) {
    __syncthreads();
    for (int i = tid; i < 16 * 256; i += 256) {   // 16c x 4row x 64w
      int c = i >> 8, r = (i >> 6) & 3, w = i & 63;
      int row = h0 - 1 + r;
      float v = 0.f;
      if (row >= 0 && row < HW)
        v = x[((size_t)(b * CIN + c0 + cc + c) << 12) + row * HW + w];
      xs[c][r][w + 1] = v;
    }
    if (tid < 128) {                  // halo zero
      int c = tid >> 3, r = (tid >> 1) & 3, s = tid & 1;
      xs[c][r][s ? 65 : 0] = 0.f;
    }
    for (int i = tid; i < 16 * 9 * 32; i += 256) {
      int c = i / 288, rem = i - c * 288, tap = rem >> 5, d = rem & 31;
      wl[c][tap][d] = cw[(size_t)(d0 + d) * 2304 + (c0 + cc + c) * 9 + tap];
    }
    __syncthreads();

#pragma unroll 2
    for (int c = 0; c < 16; ++c) {
      float xv[4][4];
#pragma unroll
      for (int r = 0; r < 4; ++r) {
        float2 p0 = *(const float2*)&xs[c][r][w0];
        float2 p1 = *(const float2*)&xs[c][r][w0 + 2];
        xv[r][0] = p0.x; xv[r][1] = p0.y; xv[r][2] = p1.x; xv[r][3] = p1.y;
      }
#pragma unroll
      for (int tap = 0; tap < 9; ++tap) {
        const int kh = tap / 3, kw = tap - kh * 3;
        float4 wv = *(const float4*)&wl[c][tap][dq * 4];
        float wf[4] = {wv.x, wv.y, wv.z, wv.w};
#pragma unroll
        for (int hi = 0; hi < 2; ++hi)
#pragma unroll
          for (int wi = 0; wi < 2; ++wi) {
            float xvv = xv[hi + kh][wi + kw];
#pragma unroll
            for (int di = 0; di < 4; ++di)
              acc[hi][wi][di] = fmaf(wf[di], xvv, acc[hi][wi][di]);
          }
      }
    }
  }
#pragma unroll
  for (int di = 0; di < 4; ++di) {
    int d = d0 + dq * 4 + di;
#pragma unroll
    for (int hi = 0; hi < 2; ++hi)
#pragma unroll
      for (int wi = 0; wi < 2; ++wi)
        pp[((size_t)((b * 4 + cs) * 64 + d) << 12) + (h0 + hi) * HW + w0 + wi] =
            acc[hi][wi][di];
  }
}

// ---------------------------------------------------------------------------
// K2: reduce c-split partials + bias + BN + PReLU -> e[b][d][n]
// ---------------------------------------------------------------------------
__global__ __launch_bounds__(256) void k_bn(
    const float* __restrict__ pp, const float* __restrict__ cb,
    const float* __restrict__ gamma, const float* __restrict__ beta,
    const float* __restrict__ mean, const float* __restrict__ var,
    const float* __restrict__ pw, float* __restrict__ e) {
  const int flat = blockIdx.x * 256 + threadIdx.x;   // [b][d][n]
  const int b = flat >> 18;
  const int d = (flat >> 12) & 63;
  const int n = flat & 4095;
  float s = 0.f;
#pragma unroll
  for (int cs = 0; cs < 4; ++cs)
    s += pp[((size_t)((b * 4 + cs) * 64 + d) << 12) + n];
  float scale = gamma[d] / sqrtf(var[d] + 1e-5f);
  float y = (s + cb[d] - mean[d]) * scale + beta[d];
  y = (y >= 0.f) ? y : pw[0] * y;
  e[((size_t)(b * CR + d) << 12) + n] = y;
}

// ---------------------------------------------------------------------------
// K3: Gram sim = e^T e (fp32), unchanged from round 2
// ---------------------------------------------------------------------------
__global__ __launch_bounds__(256) void k_gram(const float* __restrict__ e,
                                              float* __restrict__ sim) {
  const int bm = blockIdx.x, bn = blockIdx.y, b = blockIdx.z;
  __shared__ __align__(16) float at[CR][64];
  __shared__ __align__(16) float bt[CR][64];
  const float* eb = e + (size_t)b * CR * NPIX;
  const int tid = threadIdx.x;
  for (int i = tid; i < CR * 64; i += 256) {
    int d = i >> 6, col = i & 63;
    at[d][col] = eb[(size_t)d * NPIX + bn * 64 + col];
    bt[d][col] = eb[(size_t)d * NPIX + bm * 64 + col];
  }
  __syncthreads();
  const int tx = tid & 15, ty = tid >> 4;
  float acc[4][4] = {};
  for (int d = 0; d < CR; ++d) {
    float4 a4 = *(const float4*)&at[d][ty * 4];
    float4 b4 = *(const float4*)&bt[d][tx * 4];
    float av[4] = {a4.x, a4.y, a4.z, a4.w};
    float bv[4] = {b4.x, b4.y, b4.z, b4.w};
#pragma unroll
    for (int i = 0; i < 4; ++i)
#pragma unroll
      for (int j = 0; j < 4; ++j) acc[i][j] = fmaf(av[i], bv[j], acc[i][j]);
  }
  float* sb = sim + (size_t)b * NPIX * NPIX;
#pragma unroll
  for (int i = 0; i < 4; ++i) {
    int n = bn * 64 + ty * 4 + i;
    float4 o = make_float4(acc[i][0], acc[i][1], acc[i][2], acc[i][3]);
    *(float4*)&sb[(size_t)n * NPIX + bm * 64 + tx * 4] = o;
  }
}

// ---------------------------------------------------------------------------
// K4: row-wise sparsemax (Michelot, exact). Writes p IN PLACE as bf16 into
// the first 8KB of each row's 16KB slot (block owns its row exclusively;
// all reads precede writes).
// ---------------------------------------------------------------------------
__global__ __launch_bounds__(256) void k_sparsemax(float* __restrict__ sim) {
  float* rp = sim + (size_t)blockIdx.x * NPIX;
  const int tid = threadIdx.x;
  const int lane = tid & 63, wid = tid >> 6;

  float v[16];
  const float4* rv = (const float4*)rp;
#pragma unroll
  for (int i = 0; i < 4; ++i) {
    float4 t = rv[tid + i * 256];
    v[i * 4 + 0] = t.x; v[i * 4 + 1] = t.y;
    v[i * 4 + 2] = t.z; v[i * 4 + 3] = t.w;
  }

  __shared__ float ssum[4];
  __shared__ int   scnt[4];
  __shared__ float stau;
  __shared__ int   sctot;

  float lsum = 0.f;
#pragma unroll
  for (int i = 0; i < 16; ++i) lsum += v[i];
  for (int o = 32; o > 0; o >>= 1) lsum += __shfl_down(lsum, o);
  if (lane == 0) ssum[wid] = lsum;
  __syncthreads();
  if (tid == 0)
    stau = (ssum[0] + ssum[1] + ssum[2] + ssum[3] - 1.f) * (1.f / NPIX);
  __syncthreads();
  float tau = stau;
  int cnt_prev = NPIX;

  for (int it = 0; it < 128; ++it) {
    float ls = 0.f; int lc = 0;
#pragma unroll
    for (int i = 0; i < 16; ++i)
      if (v[i] > tau) { ls += v[i]; ++lc; }
    for (int o = 32; o > 0; o >>= 1) {
      ls += __shfl_down(ls, o);
      lc += __shfl_down(lc, o);
    }
    if (lane == 0) { ssum[wid] = ls; scnt[wid] = lc; }
    __syncthreads();
    if (tid == 0) {
      float s = ssum[0] + ssum[1] + ssum[2] + ssum[3];
      int   c = scnt[0] + scnt[1] + scnt[2] + scnt[3];
      sctot = c;
      stau = (s - 1.f) / (float)c;
    }
    __syncthreads();
    int c = sctot;
    tau = stau;
    if (c == cnt_prev) break;
    cnt_prev = c;
  }

  unsigned short* wp = (unsigned short*)rp;
#pragma unroll
  for (int i = 0; i < 4; ++i) {
    int base = 4 * (tid + i * 256);
    ushort4 t;
    t.x = f2bf(fmaxf(v[i * 4 + 0] - tau, 0.f));
    t.y = f2bf(fmaxf(v[i * 4 + 1] - tau, 0.f));
    t.z = f2bf(fmaxf(v[i * 4 + 2] - tau, 0.f));
    t.w = f2bf(fmaxf(v[i * 4 + 3] - tau, 0.f));
    *(ushort4*)&wp[base] = t;
  }
}

// ---------------------------------------------------------------------------
// K5: out[b][c][m] = sum_n x[c][n] p[n][m] + x[c][m], bf16 MFMA 16x16x32.
// A = x cast in-reg -> LDS [64][40] K-major. B = p bf16 rows (stride 8192
// ushorts) transposed in-reg -> LDS [128][40] K-major. 4 waves, wave=32x64.
// ---------------------------------------------------------------------------
__global__ __launch_bounds__(256) void k_out_mfma(
    const unsigned short* __restrict__ pb, const float* __restrict__ x,
    float* __restrict__ out) {
  const int m0 = blockIdx.x * 128;
  const int c0 = blockIdx.y * 64;
  const int b  = blockIdx.z;
  const int tid = threadIdx.x;
  const int l = tid & 63, wid = tid >> 6;
  const int wr = wid >> 1, wc = wid & 1;

  __shared__ unsigned short As[64][40];    // [c_local][k] +pad
  __shared__ unsigned short Bs[128][40];   // [m_local][k] +pad

  f32x4 acc[2][4];
#pragma unroll
  for (int i = 0; i < 2; ++i)
#pragma unroll
    for (int j = 0; j < 4; ++j)
#pragma unroll
      for (int q = 0; q < 4; ++q) acc[i][j][q] = 0.f;

  // A staging role: thread -> (row 0..63, k-chunk of 8)
  const int arow = tid >> 2;
  const int akc  = (tid & 3) * 8;
  const float* axsrc = x + ((size_t)(b * CIN + c0 + arow) << 12) + akc;
  // B staging role: thread -> (4 m, 4 k-rows)
  const int bm = (tid & 31) * 4;
  const int bk = (tid >> 5) * 4;
  const unsigned short* bsrc = pb + (size_t)(b * NPIX + bk) * 8192 + m0 + bm;

  for (int k0 = 0; k0 < NPIX; k0 += 32) {
    __syncthreads();
    // --- stage A: 8 floats -> bf16, one b128 LDS write
    float4 A0 = *(const float4*)(axsrc + k0);
    float4 A1 = *(const float4*)(axsrc + k0 + 4);
    s16x8 ap;
    ap[0] = (short)f2bf(A0.x); ap[1] = (short)f2bf(A0.y);
    ap[2] = (short)f2bf(A0.z); ap[3] = (short)f2bf(A0.w);
    ap[4] = (short)f2bf(A1.x); ap[5] = (short)f2bf(A1.y);
    ap[6] = (short)f2bf(A1.z); ap[7] = (short)f2bf(A1.w);
    *(s16x8*)&As[arow][akc] = ap;
    // --- stage B: 4 rows x 4 m, transpose in reg, 4 b64 LDS writes
    const unsigned short* bp = bsrc + (size_t)k0 * 8192;
    ushort4 L0 = *(const ushort4*)(bp);
    ushort4 L1 = *(const ushort4*)(bp + 8192);
    ushort4 L2 = *(const ushort4*)(bp + 16384);
    ushort4 L3 = *(const ushort4*)(bp + 24576);
    *(ushort4*)&Bs[bm + 0][bk] = make_ushort4(L0.x, L1.x, L2.x, L3.x);
    *(ushort4*)&Bs[bm + 1][bk] = make_ushort4(L0.y, L1.y, L2.y, L3.y);
    *(ushort4*)&Bs[bm + 2][bk] = make_ushort4(L0.z, L1.z, L2.z, L3.z);
    *(ushort4*)&Bs[bm + 3][bk] = make_ushort4(L0.w, L1.w, L2.w, L3.w);
    __syncthreads();

    s16x8 a[2], bb[4];
    const int kg = l >> 4;
#pragma unroll
    for (int i = 0; i < 2; ++i) {
      int row = wr * 32 + i * 16 + (l & 15);
      a[i] = *(const s16x8*)&As[row][kg * 8];
    }
#pragma unroll
    for (int j = 0; j < 4; ++j) {
      int n = wc * 64 + j * 16 + (l & 15);
      bb[j] = *(const s16x8*)&Bs[n][kg * 8];
    }
#pragma unroll
    for (int i = 0; i < 2; ++i)
#pragma unroll
      for (int j = 0; j < 4; ++j)
        acc[i][j] = __builtin_amdgcn_mfma_f32_16x16x32_bf16(
            a[i], bb[j], acc[i][j], 0, 0, 0);
  }

#pragma unroll
  for (int i = 0; i < 2; ++i)
#pragma unroll
    for (int j = 0; j < 4; ++j)
#pragma unroll
      for (int q = 0; q < 4; ++q) {
        int c = c0 + wr * 32 + i * 16 + (l >> 4) * 4 + q;
        int m = m0 + wc * 64 + j * 16 + (l & 15);
        size_t off = ((size_t)(b * CIN + c) << 12) + m;
        out[off] = acc[i][j][q] + x[off];
      }
}

// ---------------------------------------------------------------------------
extern "C" void kernel_launch(void* const* d_in, const int* in_sizes, int n_in,
                              void* d_out, int out_size, void* d_ws, size_t ws_size,
                              hipStream_t stream) {
  const float* x     = (const float*)d_in[0];
  const float* cw    = (const float*)d_in[1];
  const float* cb    = (const float*)d_in[2];
  const float* gamma = (const float*)d_in[3];
  const float* beta  = (const float*)d_in[4];
  const float* mean  = (const float*)d_in[5];
  const float* var   = (const float*)d_in[6];
  const float* pw    = (const float*)d_in[7];
  float* out = (float*)d_out;

  // ws layout: [sim 128MiB (pp 8MiB aliases head, dead before gram)] [e 2MiB]
  float* sim = (float*)d_ws;
  float* pp  = (float*)d_ws;                              // alias, ok
  float* e   = (float*)((char*)d_ws + (size_t)(128u << 20));

  k_conv_part<<<dim3(32, 2, 8), 256, 0, stream>>>(x, cw, pp);
  k_bn<<<2048, 256, 0, stream>>>(pp, cb, gamma, beta, mean, var, pw, e);
  k_gram<<<dim3(64, 64, 2), 256, 0, stream>>>(e, sim);
  k_sparsemax<<<8192, 256, 0, stream>>>(sim);
  k_out_mfma<<<dim3(32, 4, 2), 256, 0, stream>>>((const unsigned short*)sim, x, out);
}

// Round 5
// 344.001 us; speedup vs baseline: 1.9366x; 1.0608x over previous
//
#include <hip/hip_runtime.h>
#include <math.h>

#define NPIX 4096
#define CR   64
#define CIN  256
#define HW   64
#define RB   8      // sparsemax rows per block in fused kernel

typedef __attribute__((ext_vector_type(8))) short s16x8;
typedef __attribute__((ext_vector_type(4))) float f32x4;

__device__ __forceinline__ unsigned short f2bf(float f) {
  union { float f; unsigned u; } a; a.f = f;
  return (unsigned short)((a.u + 0x7FFF + ((a.u >> 16) & 1)) >> 16);
}

// ---------------------------------------------------------------------------
// K1: conv partials, c-split=4. Block: 2h x 64w x 32d over 64 channels.
// ---------------------------------------------------------------------------
__global__ __launch_bounds__(256) void k_conv_part(
    const float* __restrict__ x, const float* __restrict__ cw,
    float* __restrict__ pp) {
  const int hg = blockIdx.x;
  const int dg = blockIdx.y;
  const int b  = blockIdx.z >> 2;
  const int cs = blockIdx.z & 3;
  const int h0 = hg * 2, d0 = dg * 32, c0 = cs * 64;
  const int tid = threadIdx.x;
  const int wp = tid & 31;
  const int dq = tid >> 5;
  const int w0 = wp * 2;

  __shared__ float xs[16][4][68];
  __shared__ float wl[16][9][32];

  float acc[2][2][4] = {};

  for (int cc = 0; cc < 64; cc += 16) {
    __syncthreads();
    for (int i = tid; i < 16 * 256; i += 256) {
      int c = i >> 8, r = (i >> 6) & 3, w = i & 63;
      int row = h0 - 1 + r;
      float v = 0.f;
      if (row >= 0 && row < HW)
        v = x[((size_t)(b * CIN + c0 + cc + c) << 12) + row * HW + w];
      xs[c][r][w + 1] = v;
    }
    if (tid < 128) {
      int c = tid >> 3, r = (tid >> 1) & 3, s = tid & 1;
      xs[c][r][s ? 65 : 0] = 0.f;
    }
    for (int i = tid; i < 16 * 9 * 32; i += 256) {
      int c = i / 288, rem = i - c * 288, tap = rem >> 5, d = rem & 31;
      wl[c][tap][d] = cw[(size_t)(d0 + d) * 2304 + (c0 + cc + c) * 9 + tap];
    }
    __syncthreads();

#pragma unroll 2
    for (int c = 0; c < 16; ++c) {
      float xv[4][4];
#pragma unroll
      for (int r = 0; r < 4; ++r) {
        float2 p0 = *(const float2*)&xs[c][r][w0];
        float2 p1 = *(const float2*)&xs[c][r][w0 + 2];
        xv[r][0] = p0.x; xv[r][1] = p0.y; xv[r][2] = p1.x; xv[r][3] = p1.y;
      }
#pragma unroll
      for (int tap = 0; tap < 9; ++tap) {
        const int kh = tap / 3, kw = tap - kh * 3;
        float4 wv = *(const float4*)&wl[c][tap][dq * 4];
        float wf[4] = {wv.x, wv.y, wv.z, wv.w};
#pragma unroll
        for (int hi = 0; hi < 2; ++hi)
#pragma unroll
          for (int wi = 0; wi < 2; ++wi) {
            float xvv = xv[hi + kh][wi + kw];
#pragma unroll
            for (int di = 0; di < 4; ++di)
              acc[hi][wi][di] = fmaf(wf[di], xvv, acc[hi][wi][di]);
          }
      }
    }
  }
#pragma unroll
  for (int di = 0; di < 4; ++di) {
    int d = d0 + dq * 4 + di;
#pragma unroll
    for (int hi = 0; hi < 2; ++hi)
#pragma unroll
      for (int wi = 0; wi < 2; ++wi)
        pp[((size_t)((b * 4 + cs) * 64 + d) << 12) + (h0 + hi) * HW + w0 + wi] =
            acc[hi][wi][di];
  }
}

// ---------------------------------------------------------------------------
// K2: reduce c-split partials + bias + BN + PReLU -> e[b][d][n]
// ---------------------------------------------------------------------------
__global__ __launch_bounds__(256) void k_bn(
    const float* __restrict__ pp, const float* __restrict__ cb,
    const float* __restrict__ gamma, const float* __restrict__ beta,
    const float* __restrict__ mean, const float* __restrict__ var,
    const float* __restrict__ pw, float* __restrict__ e) {
  const int flat = blockIdx.x * 256 + threadIdx.x;
  const int b = flat >> 18;
  const int d = (flat >> 12) & 63;
  const int n = flat & 4095;
  float s = 0.f;
#pragma unroll
  for (int cs = 0; cs < 4; ++cs)
    s += pp[((size_t)((b * 4 + cs) * 64 + d) << 12) + n];
  float scale = gamma[d] / sqrtf(var[d] + 1e-5f);
  float y = (s + cb[d] - mean[d]) * scale + beta[d];
  y = (y >= 0.f) ? y : pw[0] * y;
  e[((size_t)(b * CR + d) << 12) + n] = y;
}

// ---------------------------------------------------------------------------
// K3 (fused): Gram rows + sparsemax (Michelot, exact) -> p bf16 + tile flags.
// Block = 8 rows; sim held in registers acc[8][16]/thread; e streamed from L2.
// ---------------------------------------------------------------------------
__global__ __launch_bounds__(256) void k_gsm(
    const float* __restrict__ e, unsigned short* __restrict__ p,
    unsigned char* __restrict__ flags) {
  const int n0 = blockIdx.x * RB;
  const int b  = blockIdx.y;
  const int tid = threadIdx.x;
  const int lane = tid & 63, wid = tid >> 6;
  const float* eb = e + ((size_t)b * CR << 12);

  __shared__ float er[CR][RB];
  __shared__ float ssum[4][RB];
  __shared__ int   scnt[4][RB];
  __shared__ float stau[RB];
  __shared__ int   sprev[RB];
  __shared__ int   schg;

  for (int i = tid; i < CR * RB; i += 256) {
    int d = i >> 3, r = i & (RB - 1);
    er[d][r] = eb[((size_t)d << 12) + n0 + r];
  }
  if (tid < RB) sprev[tid] = NPIX;
  __syncthreads();

  float acc[RB][16];
#pragma unroll
  for (int r = 0; r < RB; ++r)
#pragma unroll
    for (int j = 0; j < 16; ++j) acc[r][j] = 0.f;

  const int m0 = tid * 16;
  for (int d = 0; d < CR; ++d) {
    const float4* row = (const float4*)(eb + ((size_t)d << 12) + m0);
    float4 c0 = row[0], c1 = row[1], c2 = row[2], c3 = row[3];
    float cv[16] = {c0.x, c0.y, c0.z, c0.w, c1.x, c1.y, c1.z, c1.w,
                    c2.x, c2.y, c2.z, c2.w, c3.x, c3.y, c3.z, c3.w};
    float4 r0 = *(const float4*)&er[d][0];
    float4 r1 = *(const float4*)&er[d][4];
    float rv[RB] = {r0.x, r0.y, r0.z, r0.w, r1.x, r1.y, r1.z, r1.w};
#pragma unroll
    for (int r = 0; r < RB; ++r)
#pragma unroll
      for (int j = 0; j < 16; ++j)
        acc[r][j] = fmaf(rv[r], cv[j], acc[r][j]);
  }

  // initial tau from full-row sums
  float ls[RB];
#pragma unroll
  for (int r = 0; r < RB; ++r) {
    float t = 0.f;
#pragma unroll
    for (int j = 0; j < 16; ++j) t += acc[r][j];
    ls[r] = t;
  }
#pragma unroll
  for (int o = 32; o > 0; o >>= 1)
#pragma unroll
    for (int r = 0; r < RB; ++r) ls[r] += __shfl_down(ls[r], o);
  if (lane == 0)
#pragma unroll
    for (int r = 0; r < RB; ++r) ssum[wid][r] = ls[r];
  __syncthreads();
  if (tid < RB)
    stau[tid] = (ssum[0][tid] + ssum[1][tid] + ssum[2][tid] + ssum[3][tid]
                 - 1.f) * (1.f / NPIX);

  // Michelot fixed-point iterations
  for (int it = 0; it < 100; ++it) {
    __syncthreads();                         // A: stau visible
    float tl[RB];
#pragma unroll
    for (int r = 0; r < RB; ++r) tl[r] = stau[r];
    if (tid == 0) schg = 0;
    int lc[RB];
#pragma unroll
    for (int r = 0; r < RB; ++r) {
      float t = 0.f; int c = 0;
#pragma unroll
      for (int j = 0; j < 16; ++j)
        if (acc[r][j] > tl[r]) { t += acc[r][j]; ++c; }
      ls[r] = t; lc[r] = c;
    }
#pragma unroll
    for (int o = 32; o > 0; o >>= 1)
#pragma unroll
      for (int r = 0; r < RB; ++r) {
        ls[r] += __shfl_down(ls[r], o);
        lc[r] += __shfl_down(lc[r], o);
      }
    if (lane == 0)
#pragma unroll
      for (int r = 0; r < RB; ++r) { ssum[wid][r] = ls[r]; scnt[wid][r] = lc[r]; }
    __syncthreads();                         // B
    if (tid < RB) {
      float s = ssum[0][tid] + ssum[1][tid] + ssum[2][tid] + ssum[3][tid];
      int   c = scnt[0][tid] + scnt[1][tid] + scnt[2][tid] + scnt[3][tid];
      stau[tid] = (s - 1.f) / (float)c;
      if (c != sprev[tid]) { sprev[tid] = c; schg = 1; }
    }
    __syncthreads();                         // C
    if (schg == 0) break;
  }

  // write p (bf16) + tile nonzero flags
  unsigned short* pr = p + (((size_t)b << 12) + n0) * (size_t)NPIX + m0;
  int any = 0;
#pragma unroll
  for (int r = 0; r < RB; ++r) {
    float tr = stau[r];
    s16x8 o0, o1;
#pragma unroll
    for (int j = 0; j < 8; ++j) {
      float pv = fmaxf(acc[r][j] - tr, 0.f);
      any |= (pv > 0.f);
      o0[j] = (short)f2bf(pv);
    }
#pragma unroll
    for (int j = 0; j < 8; ++j) {
      float pv = fmaxf(acc[r][8 + j] - tr, 0.f);
      any |= (pv > 0.f);
      o1[j] = (short)f2bf(pv);
    }
    *(s16x8*)(pr + (size_t)r * NPIX) = o0;
    *(s16x8*)(pr + (size_t)r * NPIX + 8) = o1;
  }
  if (any)
    flags[((size_t)b << 12) | ((size_t)(tid >> 3) << 7) | (size_t)(n0 >> 5)] = 1;
}

// ---------------------------------------------------------------------------
// K4: out = x @ p + x, bf16 MFMA 16x16x32, skipping all-zero p k-tiles.
// ---------------------------------------------------------------------------
__global__ __launch_bounds__(256) void k_out_mfma(
    const unsigned short* __restrict__ pb, const float* __restrict__ x,
    float* __restrict__ out, const unsigned char* __restrict__ flags) {
  const int m0 = blockIdx.x * 128;
  const int c0 = blockIdx.y * 64;
  const int b  = blockIdx.z;
  const int tid = threadIdx.x;
  const int l = tid & 63, wid = tid >> 6;
  const int wr = wid >> 1, wc = wid & 1;

  __shared__ unsigned short As[64][42];
  __shared__ unsigned short Bs[128][42];
  __shared__ unsigned char fl[128];

  if (tid < 128)
    fl[tid] = flags[((size_t)b << 12) | ((size_t)blockIdx.x << 7) | (size_t)tid];

  f32x4 acc[2][4];
#pragma unroll
  for (int i = 0; i < 2; ++i)
#pragma unroll
    for (int j = 0; j < 4; ++j)
#pragma unroll
      for (int q = 0; q < 4; ++q) acc[i][j][q] = 0.f;

  const int arow = tid >> 2;
  const int akc  = (tid & 3) * 8;
  const float* axsrc = x + ((size_t)(b * CIN + c0 + arow) << 12) + akc;
  const int bm = (tid & 31) * 4;
  const int bk = (tid >> 5) * 4;
  const unsigned short* bsrc = pb + ((size_t)(b * NPIX + bk) << 12) + m0 + bm;

  __syncthreads();                    // fl ready

  for (int k0 = 0; k0 < NPIX; k0 += 32) {
    if (!fl[k0 >> 5]) continue;       // block-uniform skip
    __syncthreads();
    float4 A0 = *(const float4*)(axsrc + k0);
    float4 A1 = *(const float4*)(axsrc + k0 + 4);
    s16x8 ap;
    ap[0] = (short)f2bf(A0.x); ap[1] = (short)f2bf(A0.y);
    ap[2] = (short)f2bf(A0.z); ap[3] = (short)f2bf(A0.w);
    ap[4] = (short)f2bf(A1.x); ap[5] = (short)f2bf(A1.y);
    ap[6] = (short)f2bf(A1.z); ap[7] = (short)f2bf(A1.w);
    *(s16x8*)&As[arow][akc] = ap;
    const unsigned short* bp = bsrc + ((size_t)k0 << 12);
    ushort4 L0 = *(const ushort4*)(bp);
    ushort4 L1 = *(const ushort4*)(bp + 4096);
    ushort4 L2 = *(const ushort4*)(bp + 8192);
    ushort4 L3 = *(const ushort4*)(bp + 12288);
    *(ushort4*)&Bs[bm + 0][bk] = make_ushort4(L0.x, L1.x, L2.x, L3.x);
    *(ushort4*)&Bs[bm + 1][bk] = make_ushort4(L0.y, L1.y, L2.y, L3.y);
    *(ushort4*)&Bs[bm + 2][bk] = make_ushort4(L0.z, L1.z, L2.z, L3.z);
    *(ushort4*)&Bs[bm + 3][bk] = make_ushort4(L0.w, L1.w, L2.w, L3.w);
    __syncthreads();

    s16x8 a[2], bb[4];
    const int kg = l >> 4;
#pragma unroll
    for (int i = 0; i < 2; ++i) {
      int row = wr * 32 + i * 16 + (l & 15);
      a[i] = *(const s16x8*)&As[row][kg * 8];
    }
#pragma unroll
    for (int j = 0; j < 4; ++j) {
      int n = wc * 64 + j * 16 + (l & 15);
      bb[j] = *(const s16x8*)&Bs[n][kg * 8];
    }
#pragma unroll
    for (int i = 0; i < 2; ++i)
#pragma unroll
      for (int j = 0; j < 4; ++j)
        acc[i][j] = __builtin_amdgcn_mfma_f32_16x16x32_bf16(
            a[i], bb[j], acc[i][j], 0, 0, 0);
  }

#pragma unroll
  for (int i = 0; i < 2; ++i)
#pragma unroll
    for (int j = 0; j < 4; ++j)
#pragma unroll
      for (int q = 0; q < 4; ++q) {
        int c = c0 + wr * 32 + i * 16 + (l >> 4) * 4 + q;
        int m = m0 + wc * 64 + j * 16 + (l & 15);
        size_t off = ((size_t)(b * CIN + c) << 12) + m;
        out[off] = acc[i][j][q] + x[off];
      }
}

// ---------------------------------------------------------------------------
extern "C" void kernel_launch(void* const* d_in, const int* in_sizes, int n_in,
                              void* d_out, int out_size, void* d_ws, size_t ws_size,
                              hipStream_t stream) {
  const float* x     = (const float*)d_in[0];
  const float* cw    = (const float*)d_in[1];
  const float* cb    = (const float*)d_in[2];
  const float* gamma = (const float*)d_in[3];
  const float* beta  = (const float*)d_in[4];
  const float* mean  = (const float*)d_in[5];
  const float* var   = (const float*)d_in[6];
  const float* pw    = (const float*)d_in[7];
  float* out = (float*)d_out;

  // ws layout: p_bf16 64MiB @0 | pp 8MiB @64Mi | e 2MiB @72Mi | flags 8KiB @80Mi
  unsigned short* p_bf = (unsigned short*)d_ws;
  float* pp   = (float*)((char*)d_ws + ((size_t)64 << 20));
  float* e    = (float*)((char*)d_ws + ((size_t)72 << 20));
  unsigned char* flags = (unsigned char*)((char*)d_ws + ((size_t)80 << 20));

  hipMemsetAsync(flags, 0, 2 * 32 * 128, stream);
  k_conv_part<<<dim3(32, 2, 8), 256, 0, stream>>>(x, cw, pp);
  k_bn<<<2048, 256, 0, stream>>>(pp, cb, gamma, beta, mean, var, pw, e);
  k_gsm<<<dim3(NPIX / RB, 2), 256, 0, stream>>>(e, p_bf, flags);
  k_out_mfma<<<dim3(32, 4, 2), 256, 0, stream>>>(p_bf, x, out, flags);
}

// Round 7
// 286.050 us; speedup vs baseline: 2.3290x; 1.2026x over previous
//
#include <hip/hip_runtime.h>
#include <math.h>

#define NPIX 4096
#define CR   64
#define CIN  256
#define HW   64
#define RB   8      // sparsemax rows per block in fused kernel
#define CSPLIT 8    // conv c-split partials

typedef __attribute__((ext_vector_type(8))) short s16x8;
typedef __attribute__((ext_vector_type(4))) float f32x4;

__device__ __forceinline__ unsigned short f2bf(float f) {
  union { float f; unsigned u; } a; a.f = f;
  return (unsigned short)((a.u + 0x7FFF + ((a.u >> 16) & 1)) >> 16);
}

// ---------------------------------------------------------------------------
// K1: conv partials, c-split=8. Block: 2h x 64w x 32d over 32 channels.
// ---------------------------------------------------------------------------
__global__ __launch_bounds__(256) void k_conv_part(
    const float* __restrict__ x, const float* __restrict__ cw,
    float* __restrict__ pp) {
  const int hg = blockIdx.x;
  const int dg = blockIdx.y;
  const int b  = blockIdx.z >> 3;
  const int cs = blockIdx.z & 7;
  const int h0 = hg * 2, d0 = dg * 32, c0 = cs * 32;
  const int tid = threadIdx.x;
  const int wp = tid & 31;
  const int dq = tid >> 5;
  const int w0 = wp * 2;

  __shared__ float xs[16][4][68];
  __shared__ float wl[16][9][32];

  float acc[2][2][4] = {};

  for (int cc = 0; cc < 32; cc += 16) {
    __syncthreads();
    for (int i = tid; i < 16 * 256; i += 256) {
      int c = i >> 8, r = (i >> 6) & 3, w = i & 63;
      int row = h0 - 1 + r;
      float v = 0.f;
      if (row >= 0 && row < HW)
        v = x[((size_t)(b * CIN + c0 + cc + c) << 12) + row * HW + w];
      xs[c][r][w + 1] = v;
    }
    if (tid < 128) {
      int c = tid >> 3, r = (tid >> 1) & 3, s = tid & 1;
      xs[c][r][s ? 65 : 0] = 0.f;
    }
    for (int i = tid; i < 16 * 9 * 32; i += 256) {
      int c = i / 288, rem = i - c * 288, tap = rem >> 5, d = rem & 31;
      wl[c][tap][d] = cw[(size_t)(d0 + d) * 2304 + (c0 + cc + c) * 9 + tap];
    }
    __syncthreads();

#pragma unroll 2
    for (int c = 0; c < 16; ++c) {
      float xv[4][4];
#pragma unroll
      for (int r = 0; r < 4; ++r) {
        float2 p0 = *(const float2*)&xs[c][r][w0];
        float2 p1 = *(const float2*)&xs[c][r][w0 + 2];
        xv[r][0] = p0.x; xv[r][1] = p0.y; xv[r][2] = p1.x; xv[r][3] = p1.y;
      }
#pragma unroll
      for (int tap = 0; tap < 9; ++tap) {
        const int kh = tap / 3, kw = tap - kh * 3;
        float4 wv = *(const float4*)&wl[c][tap][dq * 4];
        float wf[4] = {wv.x, wv.y, wv.z, wv.w};
#pragma unroll
        for (int hi = 0; hi < 2; ++hi)
#pragma unroll
          for (int wi = 0; wi < 2; ++wi) {
            float xvv = xv[hi + kh][wi + kw];
#pragma unroll
            for (int di = 0; di < 4; ++di)
              acc[hi][wi][di] = fmaf(wf[di], xvv, acc[hi][wi][di]);
          }
      }
    }
  }
#pragma unroll
  for (int di = 0; di < 4; ++di) {
    int d = d0 + dq * 4 + di;
#pragma unroll
    for (int hi = 0; hi < 2; ++hi)
#pragma unroll
      for (int wi = 0; wi < 2; ++wi)
        pp[((size_t)((b * CSPLIT + cs) * 64 + d) << 12) + (h0 + hi) * HW + w0 + wi] =
            acc[hi][wi][di];
  }
}

// ---------------------------------------------------------------------------
// K2: reduce c-split partials + bias + BN + PReLU -> e[b][d][n]
// ---------------------------------------------------------------------------
__global__ __launch_bounds__(256) void k_bn(
    const float* __restrict__ pp, const float* __restrict__ cb,
    const float* __restrict__ gamma, const float* __restrict__ beta,
    const float* __restrict__ mean, const float* __restrict__ var,
    const float* __restrict__ pw, float* __restrict__ e) {
  const int flat = blockIdx.x * 256 + threadIdx.x;
  const int b = flat >> 18;
  const int d = (flat >> 12) & 63;
  const int n = flat & 4095;
  float s = 0.f;
#pragma unroll
  for (int cs = 0; cs < CSPLIT; ++cs)
    s += pp[((size_t)((b * CSPLIT + cs) * 64 + d) << 12) + n];
  float scale = gamma[d] / sqrtf(var[d] + 1e-5f);
  float y = (s + cb[d] - mean[d]) * scale + beta[d];
  y = (y >= 0.f) ? y : pw[0] * y;
  e[((size_t)(b * CR + d) << 12) + n] = y;
}

// ---------------------------------------------------------------------------
// K3 (fused): Gram rows + sparsemax (Michelot, exact) -> p bf16 + tile flags.
// tau init = rowmax - 1 (valid superset start; support is tiny -> ~2 iters).
// ---------------------------------------------------------------------------
__global__ __launch_bounds__(256) void k_gsm(
    const float* __restrict__ e, unsigned short* __restrict__ p,
    unsigned char* __restrict__ flags) {
  const int n0 = blockIdx.x * RB;
  const int b  = blockIdx.y;
  const int tid = threadIdx.x;
  const int lane = tid & 63, wid = tid >> 6;
  const float* eb = e + ((size_t)b * CR << 12);

  __shared__ float er[CR][RB];
  __shared__ float ssum[4][RB];
  __shared__ int   scnt[4][RB];
  __shared__ float stau[RB];
  __shared__ int   sprev[RB];
  __shared__ int   schg;

  for (int i = tid; i < CR * RB; i += 256) {
    int d = i >> 3, r = i & (RB - 1);
    er[d][r] = eb[((size_t)d << 12) + n0 + r];
  }
  if (tid < RB) sprev[tid] = NPIX;
  __syncthreads();

  float acc[RB][16];
#pragma unroll
  for (int r = 0; r < RB; ++r)
#pragma unroll
    for (int j = 0; j < 16; ++j) acc[r][j] = 0.f;

  const int m0 = tid * 16;
  for (int d = 0; d < CR; ++d) {
    const float4* row = (const float4*)(eb + ((size_t)d << 12) + m0);
    float4 c0 = row[0], c1 = row[1], c2 = row[2], c3 = row[3];
    float cv[16] = {c0.x, c0.y, c0.z, c0.w, c1.x, c1.y, c1.z, c1.w,
                    c2.x, c2.y, c2.z, c2.w, c3.x, c3.y, c3.z, c3.w};
    float4 r0 = *(const float4*)&er[d][0];
    float4 r1 = *(const float4*)&er[d][4];
    float rv[RB] = {r0.x, r0.y, r0.z, r0.w, r1.x, r1.y, r1.z, r1.w};
#pragma unroll
    for (int r = 0; r < RB; ++r)
#pragma unroll
      for (int j = 0; j < 16; ++j)
        acc[r][j] = fmaf(rv[r], cv[j], acc[r][j]);
  }

  // tau init = rowmax - 1
  float lm[RB];
#pragma unroll
  for (int r = 0; r < RB; ++r) {
    float m = acc[r][0];
#pragma unroll
    for (int j = 1; j < 16; ++j) m = fmaxf(m, acc[r][j]);
    lm[r] = m;
  }
#pragma unroll
  for (int o = 32; o > 0; o >>= 1)
#pragma unroll
    for (int r = 0; r < RB; ++r) lm[r] = fmaxf(lm[r], __shfl_down(lm[r], o));
  if (lane == 0)
#pragma unroll
    for (int r = 0; r < RB; ++r) ssum[wid][r] = lm[r];
  __syncthreads();
  if (tid < RB)
    stau[tid] = fmaxf(fmaxf(ssum[0][tid], ssum[1][tid]),
                      fmaxf(ssum[2][tid], ssum[3][tid])) - 1.0f;

  // Michelot fixed-point iterations (monotone tau increase, sets shrink)
  float ls[RB];
  for (int it = 0; it < 100; ++it) {
    __syncthreads();                         // A: stau visible
    float tl[RB];
#pragma unroll
    for (int r = 0; r < RB; ++r) tl[r] = stau[r];
    if (tid == 0) schg = 0;
    int lc[RB];
#pragma unroll
    for (int r = 0; r < RB; ++r) {
      float t = 0.f; int c = 0;
#pragma unroll
      for (int j = 0; j < 16; ++j)
        if (acc[r][j] > tl[r]) { t += acc[r][j]; ++c; }
      ls[r] = t; lc[r] = c;
    }
#pragma unroll
    for (int o = 32; o > 0; o >>= 1)
#pragma unroll
      for (int r = 0; r < RB; ++r) {
        ls[r] += __shfl_down(ls[r], o);
        lc[r] += __shfl_down(lc[r], o);
      }
    if (lane == 0)
#pragma unroll
      for (int r = 0; r < RB; ++r) { ssum[wid][r] = ls[r]; scnt[wid][r] = lc[r]; }
    __syncthreads();                         // B
    if (tid < RB) {
      float s = ssum[0][tid] + ssum[1][tid] + ssum[2][tid] + ssum[3][tid];
      int   c = scnt[0][tid] + scnt[1][tid] + scnt[2][tid] + scnt[3][tid];
      stau[tid] = (s - 1.f) / (float)c;
      if (c != sprev[tid]) { sprev[tid] = c; schg = 1; }
    }
    __syncthreads();                         // C
    if (schg == 0) break;
  }

  // write p (bf16) + tile nonzero flags
  unsigned short* pr = p + (((size_t)b << 12) + n0) * (size_t)NPIX + m0;
  int any = 0;
#pragma unroll
  for (int r = 0; r < RB; ++r) {
    float tr = stau[r];
    s16x8 o0, o1;
#pragma unroll
    for (int j = 0; j < 8; ++j) {
      float pv = fmaxf(acc[r][j] - tr, 0.f);
      any |= (pv > 0.f);
      o0[j] = (short)f2bf(pv);
    }
#pragma unroll
    for (int j = 0; j < 8; ++j) {
      float pv = fmaxf(acc[r][8 + j] - tr, 0.f);
      any |= (pv > 0.f);
      o1[j] = (short)f2bf(pv);
    }
    *(s16x8*)(pr + (size_t)r * NPIX) = o0;
    *(s16x8*)(pr + (size_t)r * NPIX + 8) = o1;
  }
  if (any)
    flags[((size_t)b << 12) | ((size_t)(tid >> 3) << 7) | (size_t)(n0 >> 5)] = 1;
}

// ---------------------------------------------------------------------------
// K4: out = x @ p + x, bf16 MFMA 16x16x32, skipping all-zero p k-tiles.
// ---------------------------------------------------------------------------
__global__ __launch_bounds__(256) void k_out_mfma(
    const unsigned short* __restrict__ pb, const float* __restrict__ x,
    float* __restrict__ out, const unsigned char* __restrict__ flags) {
  const int m0 = blockIdx.x * 128;
  const int c0 = blockIdx.y * 64;
  const int b  = blockIdx.z;
  const int tid = threadIdx.x;
  const int l = tid & 63, wid = tid >> 6;
  const int wr = wid >> 1, wc = wid & 1;

  __shared__ unsigned short As[64][42];
  __shared__ unsigned short Bs[128][42];
  __shared__ unsigned char fl[128];

  if (tid < 128)
    fl[tid] = flags[((size_t)b << 12) | ((size_t)blockIdx.x << 7) | (size_t)tid];

  f32x4 acc[2][4];
#pragma unroll
  for (int i = 0; i < 2; ++i)
#pragma unroll
    for (int j = 0; j < 4; ++j)
#pragma unroll
      for (int q = 0; q < 4; ++q) acc[i][j][q] = 0.f;

  const int arow = tid >> 2;
  const int akc  = (tid & 3) * 8;
  const float* axsrc = x + ((size_t)(b * CIN + c0 + arow) << 12) + akc;
  const int bm = (tid & 31) * 4;
  const int bk = (tid >> 5) * 4;
  const unsigned short* bsrc = pb + ((size_t)(b * NPIX + bk) << 12) + m0 + bm;

  __syncthreads();                    // fl ready

  for (int k0 = 0; k0 < NPIX; k0 += 32) {
    if (!fl[k0 >> 5]) continue;       // block-uniform skip
    __syncthreads();
    float4 A0 = *(const float4*)(axsrc + k0);
    float4 A1 = *(const float4*)(axsrc + k0 + 4);
    s16x8 ap;
    ap[0] = (short)f2bf(A0.x); ap[1] = (short)f2bf(A0.y);
    ap[2] = (short)f2bf(A0.z); ap[3] = (short)f2bf(A0.w);
    ap[4] = (short)f2bf(A1.x); ap[5] = (short)f2bf(A1.y);
    ap[6] = (short)f2bf(A1.z); ap[7] = (short)f2bf(A1.w);
    *(s16x8*)&As[arow][akc] = ap;
    const unsigned short* bp = bsrc + ((size_t)k0 << 12);
    ushort4 L0 = *(const ushort4*)(bp);
    ushort4 L1 = *(const ushort4*)(bp + 4096);
    ushort4 L2 = *(const ushort4*)(bp + 8192);
    ushort4 L3 = *(const ushort4*)(bp + 12288);
    *(ushort4*)&Bs[bm + 0][bk] = make_ushort4(L0.x, L1.x, L2.x, L3.x);
    *(ushort4*)&Bs[bm + 1][bk] = make_ushort4(L0.y, L1.y, L2.y, L3.y);
    *(ushort4*)&Bs[bm + 2][bk] = make_ushort4(L0.z, L1.z, L2.z, L3.z);
    *(ushort4*)&Bs[bm + 3][bk] = make_ushort4(L0.w, L1.w, L2.w, L3.w);
    __syncthreads();

    s16x8 a[2], bb[4];
    const int kg = l >> 4;
#pragma unroll
    for (int i = 0; i < 2; ++i) {
      int row = wr * 32 + i * 16 + (l & 15);
      a[i] = *(const s16x8*)&As[row][kg * 8];
    }
#pragma unroll
    for (int j = 0; j < 4; ++j) {
      int n = wc * 64 + j * 16 + (l & 15);
      bb[j] = *(const s16x8*)&Bs[n][kg * 8];
    }
#pragma unroll
    for (int i = 0; i < 2; ++i)
#pragma unroll
      for (int j = 0; j < 4; ++j)
        acc[i][j] = __builtin_amdgcn_mfma_f32_16x16x32_bf16(
            a[i], bb[j], acc[i][j], 0, 0, 0);
  }

#pragma unroll
  for (int i = 0; i < 2; ++i)
#pragma unroll
    for (int j = 0; j < 4; ++j)
#pragma unroll
      for (int q = 0; q < 4; ++q) {
        int c = c0 + wr * 32 + i * 16 + (l >> 4) * 4 + q;
        int m = m0 + wc * 64 + j * 16 + (l & 15);
        size_t off = ((size_t)(b * CIN + c) << 12) + m;
        out[off] = acc[i][j][q] + x[off];
      }
}

// ---------------------------------------------------------------------------
extern "C" void kernel_launch(void* const* d_in, const int* in_sizes, int n_in,
                              void* d_out, int out_size, void* d_ws, size_t ws_size,
                              hipStream_t stream) {
  const float* x     = (const float*)d_in[0];
  const float* cw    = (const float*)d_in[1];
  const float* cb    = (const float*)d_in[2];
  const float* gamma = (const float*)d_in[3];
  const float* beta  = (const float*)d_in[4];
  const float* mean  = (const float*)d_in[5];
  const float* var   = (const float*)d_in[6];
  const float* pw    = (const float*)d_in[7];
  float* out = (float*)d_out;

  // ws: p_bf16 64MiB @0 | pp 16MiB @64Mi | e 2MiB @80Mi | flags 8KiB @84Mi
  unsigned short* p_bf = (unsigned short*)d_ws;
  float* pp   = (float*)((char*)d_ws + ((size_t)64 << 20));
  float* e    = (float*)((char*)d_ws + ((size_t)80 << 20));
  unsigned char* flags = (unsigned char*)((char*)d_ws + ((size_t)84 << 20));

  hipMemsetAsync(flags, 0, 2 * 32 * 128, stream);
  k_conv_part<<<dim3(32, 2, 16), 256, 0, stream>>>(x, cw, pp);
  k_bn<<<2048, 256, 0, stream>>>(pp, cb, gamma, beta, mean, var, pw, e);
  k_gsm<<<dim3(NPIX / RB, 2), 256, 0, stream>>>(e, p_bf, flags);
  k_out_mfma<<<dim3(32, 4, 2), 256, 0, stream>>>(p_bf, x, out, flags);
}

// Round 8
// 273.001 us; speedup vs baseline: 2.4403x; 1.0478x over previous
//
#include <hip/hip_runtime.h>
#include <math.h>

#define NPIX 4096
#define CR   64
#define CIN  256
#define HW   64
#define RB   8      // sparsemax rows per block in fused kernel
#define CSPLIT 8    // conv c-split partials

typedef __attribute__((ext_vector_type(8))) short s16x8;
typedef __attribute__((ext_vector_type(4))) float f32x4;

__device__ __forceinline__ unsigned short f2bf(float f) {
  union { float f; unsigned u; } a; a.f = f;
  return (unsigned short)((a.u + 0x7FFF + ((a.u >> 16) & 1)) >> 16);
}

// ---------------------------------------------------------------------------
// K1: conv partials, c-split=8. Block: 2h x 64w x 32d over 32 channels.
// ---------------------------------------------------------------------------
__global__ __launch_bounds__(256) void k_conv_part(
    const float* __restrict__ x, const float* __restrict__ cw,
    float* __restrict__ pp) {
  const int hg = blockIdx.x;
  const int dg = blockIdx.y;
  const int b  = blockIdx.z >> 3;
  const int cs = blockIdx.z & 7;
  const int h0 = hg * 2, d0 = dg * 32, c0 = cs * 32;
  const int tid = threadIdx.x;
  const int wp = tid & 31;
  const int dq = tid >> 5;
  const int w0 = wp * 2;

  __shared__ float xs[16][4][68];
  __shared__ float wl[16][9][32];

  float acc[2][2][4] = {};

  for (int cc = 0; cc < 32; cc += 16) {
    __syncthreads();
    for (int i = tid; i < 16 * 256; i += 256) {
      int c = i >> 8, r = (i >> 6) & 3, w = i & 63;
      int row = h0 - 1 + r;
      float v = 0.f;
      if (row >= 0 && row < HW)
        v = x[((size_t)(b * CIN + c0 + cc + c) << 12) + row * HW + w];
      xs[c][r][w + 1] = v;
    }
    if (tid < 128) {
      int c = tid >> 3, r = (tid >> 1) & 3, s = tid & 1;
      xs[c][r][s ? 65 : 0] = 0.f;
    }
    for (int i = tid; i < 16 * 9 * 32; i += 256) {
      int c = i / 288, rem = i - c * 288, tap = rem >> 5, d = rem & 31;
      wl[c][tap][d] = cw[(size_t)(d0 + d) * 2304 + (c0 + cc + c) * 9 + tap];
    }
    __syncthreads();

#pragma unroll 2
    for (int c = 0; c < 16; ++c) {
      float xv[4][4];
#pragma unroll
      for (int r = 0; r < 4; ++r) {
        float2 p0 = *(const float2*)&xs[c][r][w0];
        float2 p1 = *(const float2*)&xs[c][r][w0 + 2];
        xv[r][0] = p0.x; xv[r][1] = p0.y; xv[r][2] = p1.x; xv[r][3] = p1.y;
      }
#pragma unroll
      for (int tap = 0; tap < 9; ++tap) {
        const int kh = tap / 3, kw = tap - kh * 3;
        float4 wv = *(const float4*)&wl[c][tap][dq * 4];
        float wf[4] = {wv.x, wv.y, wv.z, wv.w};
#pragma unroll
        for (int hi = 0; hi < 2; ++hi)
#pragma unroll
          for (int wi = 0; wi < 2; ++wi) {
            float xvv = xv[hi + kh][wi + kw];
#pragma unroll
            for (int di = 0; di < 4; ++di)
              acc[hi][wi][di] = fmaf(wf[di], xvv, acc[hi][wi][di]);
          }
      }
    }
  }
#pragma unroll
  for (int di = 0; di < 4; ++di) {
    int d = d0 + dq * 4 + di;
#pragma unroll
    for (int hi = 0; hi < 2; ++hi)
#pragma unroll
      for (int wi = 0; wi < 2; ++wi)
        pp[((size_t)((b * CSPLIT + cs) * 64 + d) << 12) + (h0 + hi) * HW + w0 + wi] =
            acc[hi][wi][di];
  }
}

// ---------------------------------------------------------------------------
// K2: reduce c-split partials + bias + BN + PReLU -> e[b][d][n]
// ---------------------------------------------------------------------------
__global__ __launch_bounds__(256) void k_bn(
    const float* __restrict__ pp, const float* __restrict__ cb,
    const float* __restrict__ gamma, const float* __restrict__ beta,
    const float* __restrict__ mean, const float* __restrict__ var,
    const float* __restrict__ pw, float* __restrict__ e) {
  const int flat = blockIdx.x * 256 + threadIdx.x;
  const int b = flat >> 18;
  const int d = (flat >> 12) & 63;
  const int n = flat & 4095;
  float s = 0.f;
#pragma unroll
  for (int cs = 0; cs < CSPLIT; ++cs)
    s += pp[((size_t)((b * CSPLIT + cs) * 64 + d) << 12) + n];
  float scale = gamma[d] / sqrtf(var[d] + 1e-5f);
  float y = (s + cb[d] - mean[d]) * scale + beta[d];
  y = (y >= 0.f) ? y : pw[0] * y;
  e[((size_t)(b * CR + d) << 12) + n] = y;
}

// ---------------------------------------------------------------------------
// K3 (fused): Gram rows + sparsemax (Michelot, exact) -> p bf16 + tile flags.
// 512 threads; thread = 8 m-cols x 8 rows = 64 accs (fits VGPRs, no AGPR
// shuttle). tau init = rowmax - 1.
// ---------------------------------------------------------------------------
__global__ __launch_bounds__(512) void k_gsm(
    const float* __restrict__ e, unsigned short* __restrict__ p,
    unsigned char* __restrict__ flags) {
  const int n0 = blockIdx.x * RB;
  const int b  = blockIdx.y;
  const int tid = threadIdx.x;          // 0..511
  const int lane = tid & 63, wid = tid >> 6;   // 8 waves
  const float* eb = e + ((size_t)b * CR << 12);

  __shared__ float er[CR][RB];
  __shared__ float ssum[8][RB];
  __shared__ int   scnt[8][RB];
  __shared__ float stau[RB];
  __shared__ int   sprev[RB];
  __shared__ int   schg;

  {                                      // stage the 8 e-columns (rows n0..n0+7)
    int d = tid >> 3, r = tid & 7;
    er[d][r] = eb[((size_t)d << 12) + n0 + r];
  }
  if (tid < RB) sprev[tid] = NPIX;
  __syncthreads();

  float acc[RB][8];
#pragma unroll
  for (int r = 0; r < RB; ++r)
#pragma unroll
    for (int j = 0; j < 8; ++j) acc[r][j] = 0.f;

  const int m0 = tid * 8;
  for (int d = 0; d < CR; ++d) {
    const float4* row = (const float4*)(eb + ((size_t)d << 12) + m0);
    float4 c0 = row[0], c1 = row[1];
    float cv[8] = {c0.x, c0.y, c0.z, c0.w, c1.x, c1.y, c1.z, c1.w};
    float4 r0 = *(const float4*)&er[d][0];
    float4 r1 = *(const float4*)&er[d][4];
    float rv[RB] = {r0.x, r0.y, r0.z, r0.w, r1.x, r1.y, r1.z, r1.w};
#pragma unroll
    for (int r = 0; r < RB; ++r)
#pragma unroll
      for (int j = 0; j < 8; ++j)
        acc[r][j] = fmaf(rv[r], cv[j], acc[r][j]);
  }

  // tau init = rowmax - 1
  float lm[RB];
#pragma unroll
  for (int r = 0; r < RB; ++r) {
    float m = acc[r][0];
#pragma unroll
    for (int j = 1; j < 8; ++j) m = fmaxf(m, acc[r][j]);
    lm[r] = m;
  }
#pragma unroll
  for (int o = 32; o > 0; o >>= 1)
#pragma unroll
    for (int r = 0; r < RB; ++r) lm[r] = fmaxf(lm[r], __shfl_down(lm[r], o));
  if (lane == 0)
#pragma unroll
    for (int r = 0; r < RB; ++r) ssum[wid][r] = lm[r];
  __syncthreads();
  if (tid < RB) {
    float m = ssum[0][tid];
#pragma unroll
    for (int w = 1; w < 8; ++w) m = fmaxf(m, ssum[w][tid]);
    stau[tid] = m - 1.0f;
  }

  // Michelot fixed-point iterations (monotone tau increase, sets shrink)
  float ls[RB];
  int lc[RB];
  for (int it = 0; it < 100; ++it) {
    __syncthreads();                         // A: stau visible
    float tl[RB];
#pragma unroll
    for (int r = 0; r < RB; ++r) tl[r] = stau[r];
    if (tid == 0) schg = 0;
#pragma unroll
    for (int r = 0; r < RB; ++r) {
      float t = 0.f; int c = 0;
#pragma unroll
      for (int j = 0; j < 8; ++j)
        if (acc[r][j] > tl[r]) { t += acc[r][j]; ++c; }
      ls[r] = t; lc[r] = c;
    }
#pragma unroll
    for (int o = 32; o > 0; o >>= 1)
#pragma unroll
      for (int r = 0; r < RB; ++r) {
        ls[r] += __shfl_down(ls[r], o);
        lc[r] += __shfl_down(lc[r], o);
      }
    if (lane == 0)
#pragma unroll
      for (int r = 0; r < RB; ++r) { ssum[wid][r] = ls[r]; scnt[wid][r] = lc[r]; }
    __syncthreads();                         // B
    if (tid < RB) {
      float s = 0.f; int c = 0;
#pragma unroll
      for (int w = 0; w < 8; ++w) { s += ssum[w][tid]; c += scnt[w][tid]; }
      stau[tid] = (s - 1.f) / (float)c;
      if (c != sprev[tid]) { sprev[tid] = c; schg = 1; }
    }
    __syncthreads();                         // C
    if (schg == 0) break;
  }

  // write p (bf16) + tile nonzero flags
  unsigned short* pr = p + (((size_t)b << 12) + n0) * (size_t)NPIX + m0;
  int any = 0;
#pragma unroll
  for (int r = 0; r < RB; ++r) {
    float tr = stau[r];
    s16x8 o0;
#pragma unroll
    for (int j = 0; j < 8; ++j) {
      float pv = fmaxf(acc[r][j] - tr, 0.f);
      any |= (pv > 0.f);
      o0[j] = (short)f2bf(pv);
    }
    *(s16x8*)(pr + (size_t)r * NPIX) = o0;
  }
  if (any)
    flags[((size_t)b << 12) | ((size_t)(tid >> 4) << 7) | (size_t)(n0 >> 5)] = 1;
}

// ---------------------------------------------------------------------------
// K4: out = x @ p + x, bf16 MFMA 16x16x32, skipping all-zero p k-tiles.
// ---------------------------------------------------------------------------
__global__ __launch_bounds__(256) void k_out_mfma(
    const unsigned short* __restrict__ pb, const float* __restrict__ x,
    float* __restrict__ out, const unsigned char* __restrict__ flags) {
  const int m0 = blockIdx.x * 128;
  const int c0 = blockIdx.y * 64;
  const int b  = blockIdx.z;
  const int tid = threadIdx.x;
  const int l = tid & 63, wid = tid >> 6;
  const int wr = wid >> 1, wc = wid & 1;

  __shared__ unsigned short As[64][42];
  __shared__ unsigned short Bs[128][42];
  __shared__ unsigned char fl[128];

  if (tid < 128)
    fl[tid] = flags[((size_t)b << 12) | ((size_t)blockIdx.x << 7) | (size_t)tid];

  f32x4 acc[2][4];
#pragma unroll
  for (int i = 0; i < 2; ++i)
#pragma unroll
    for (int j = 0; j < 4; ++j)
#pragma unroll
      for (int q = 0; q < 4; ++q) acc[i][j][q] = 0.f;

  const int arow = tid >> 2;
  const int akc  = (tid & 3) * 8;
  const float* axsrc = x + ((size_t)(b * CIN + c0 + arow) << 12) + akc;
  const int bm = (tid & 31) * 4;
  const int bk = (tid >> 5) * 4;
  const unsigned short* bsrc = pb + ((size_t)(b * NPIX + bk) << 12) + m0 + bm;

  __syncthreads();                    // fl ready

  for (int k0 = 0; k0 < NPIX; k0 += 32) {
    if (!fl[k0 >> 5]) continue;       // block-uniform skip
    __syncthreads();
    float4 A0 = *(const float4*)(axsrc + k0);
    float4 A1 = *(const float4*)(axsrc + k0 + 4);
    s16x8 ap;
    ap[0] = (short)f2bf(A0.x); ap[1] = (short)f2bf(A0.y);
    ap[2] = (short)f2bf(A0.z); ap[3] = (short)f2bf(A0.w);
    ap[4] = (short)f2bf(A1.x); ap[5] = (short)f2bf(A1.y);
    ap[6] = (short)f2bf(A1.z); ap[7] = (short)f2bf(A1.w);
    *(s16x8*)&As[arow][akc] = ap;
    const unsigned short* bp = bsrc + ((size_t)k0 << 12);
    ushort4 L0 = *(const ushort4*)(bp);
    ushort4 L1 = *(const ushort4*)(bp + 4096);
    ushort4 L2 = *(const ushort4*)(bp + 8192);
    ushort4 L3 = *(const ushort4*)(bp + 12288);
    *(ushort4*)&Bs[bm + 0][bk] = make_ushort4(L0.x, L1.x, L2.x, L3.x);
    *(ushort4*)&Bs[bm + 1][bk] = make_ushort4(L0.y, L1.y, L2.y, L3.y);
    *(ushort4*)&Bs[bm + 2][bk] = make_ushort4(L0.z, L1.z, L2.z, L3.z);
    *(ushort4*)&Bs[bm + 3][bk] = make_ushort4(L0.w, L1.w, L2.w, L3.w);
    __syncthreads();

    s16x8 a[2], bb[4];
    const int kg = l >> 4;
#pragma unroll
    for (int i = 0; i < 2; ++i) {
      int row = wr * 32 + i * 16 + (l & 15);
      a[i] = *(const s16x8*)&As[row][kg * 8];
    }
#pragma unroll
    for (int j = 0; j < 4; ++j) {
      int n = wc * 64 + j * 16 + (l & 15);
      bb[j] = *(const s16x8*)&Bs[n][kg * 8];
    }
#pragma unroll
    for (int i = 0; i < 2; ++i)
#pragma unroll
      for (int j = 0; j < 4; ++j)
        acc[i][j] = __builtin_amdgcn_mfma_f32_16x16x32_bf16(
            a[i], bb[j], acc[i][j], 0, 0, 0);
  }

#pragma unroll
  for (int i = 0; i < 2; ++i)
#pragma unroll
    for (int j = 0; j < 4; ++j)
#pragma unroll
      for (int q = 0; q < 4; ++q) {
        int c = c0 + wr * 32 + i * 16 + (l >> 4) * 4 + q;
        int m = m0 + wc * 64 + j * 16 + (l & 15);
        size_t off = ((size_t)(b * CIN + c) << 12) + m;
        out[off] = acc[i][j][q] + x[off];
      }
}

// ---------------------------------------------------------------------------
extern "C" void kernel_launch(void* const* d_in, const int* in_sizes, int n_in,
                              void* d_out, int out_size, void* d_ws, size_t ws_size,
                              hipStream_t stream) {
  const float* x     = (const float*)d_in[0];
  const float* cw    = (const float*)d_in[1];
  const float* cb    = (const float*)d_in[2];
  const float* gamma = (const float*)d_in[3];
  const float* beta  = (const float*)d_in[4];
  const float* mean  = (const float*)d_in[5];
  const float* var   = (const float*)d_in[6];
  const float* pw    = (const float*)d_in[7];
  float* out = (float*)d_out;

  // ws: p_bf16 64MiB @0 | pp 16MiB @64Mi | e 2MiB @80Mi | flags 8KiB @84Mi
  unsigned short* p_bf = (unsigned short*)d_ws;
  float* pp   = (float*)((char*)d_ws + ((size_t)64 << 20));
  float* e    = (float*)((char*)d_ws + ((size_t)80 << 20));
  unsigned char* flags = (unsigned char*)((char*)d_ws + ((size_t)84 << 20));

  hipMemsetAsync(flags, 0, 2 * 32 * 128, stream);
  k_conv_part<<<dim3(32, 2, 16), 256, 0, stream>>>(x, cw, pp);
  k_bn<<<2048, 256, 0, stream>>>(pp, cb, gamma, beta, mean, var, pw, e);
  k_gsm<<<dim3(NPIX / RB, 2), 512, 0, stream>>>(e, p_bf, flags);
  k_out_mfma<<<dim3(32, 4, 2), 256, 0, stream>>>(p_bf, x, out, flags);
}